// Round 7
// baseline (221.078 us; speedup 1.0000x reference)
//
#include <hip/hip_runtime.h>
#include <hip/hip_bf16.h>

#define N_NODES 50000
#define N_EDGES 800000
#define FEAT 64
#define NRELS 8
#define SCAN_CHUNK 1024   // elements per scanA block (256 threads x int4)
#define NBUCK 196         // ceil(50000/256) coarse buckets (dst >> 8)
#define EPB 2048          // edges per bfill block
#define WTB 32            // blocks of prep_kernel devoted to W transpose

typedef __attribute__((ext_vector_type(8))) short bf16x8;   // 8 bf16 in 4 VGPRs
typedef __attribute__((ext_vector_type(4))) float f32x4;

static __host__ __device__ inline size_t align256(size_t x) { return (x + 255) & ~(size_t)255; }

__device__ inline unsigned short f2b(float f) {   // fp32 -> bf16 RNE
    unsigned u = __builtin_bit_cast(unsigned, f);
    unsigned r = (u + 0x7fffu + ((u >> 16) & 1u)) >> 16;
    return (unsigned short)r;
}
__device__ inline float b2f(unsigned short u) {   // bf16 -> fp32
    unsigned v = ((unsigned)u) << 16;
    return __builtin_bit_cast(float, v);
}

// ---------------------------------------------------------------------------
// Kernel 1: int histogram of dst -> cnt (in-degree)
// ---------------------------------------------------------------------------
__global__ void hist_kernel(const int* __restrict__ dst, int* __restrict__ cnt, int E) {
    int e = blockIdx.x * blockDim.x + threadIdx.x;
    if (e < E) atomicAdd(cnt + dst[e], 1);
}

// ---------------------------------------------------------------------------
// Scan phase A: block-local exclusive scan of cnt -> off, totals -> part
// ---------------------------------------------------------------------------
__global__ void scanA_kernel(const int* __restrict__ cnt, int* __restrict__ off,
                             int* __restrict__ part, int N) {
    __shared__ int sums[256];
    const int t = threadIdx.x;
    const int base = blockIdx.x * SCAN_CHUNK + t * 4;
    int4 v = make_int4(0, 0, 0, 0);
    if (base + 3 < N) {
        v = *(const int4*)(cnt + base);
    } else {
        if (base + 0 < N) v.x = cnt[base + 0];
        if (base + 1 < N) v.y = cnt[base + 1];
        if (base + 2 < N) v.z = cnt[base + 2];
        if (base + 3 < N) v.w = cnt[base + 3];
    }
    const int s = v.x + v.y + v.z + v.w;
    sums[t] = s;
    __syncthreads();
    for (int o = 1; o < 256; o <<= 1) {
        int u = (t >= o) ? sums[t - o] : 0;
        __syncthreads();
        sums[t] += u;
        __syncthreads();
    }
    const int ex = sums[t] - s;
    int4 w;
    w.x = ex;
    w.y = ex + v.x;
    w.z = w.y + v.y;
    w.w = w.z + v.z;
    if (base + 3 < N) {
        *(int4*)(off + base) = w;
    } else {
        if (base + 0 < N) off[base + 0] = w.x;
        if (base + 1 < N) off[base + 1] = w.y;
        if (base + 2 < N) off[base + 2] = w.z;
        if (base + 3 < N) off[base + 3] = w.w;
    }
    if (t == 255) part[blockIdx.x] = sums[255];
}

// ---------------------------------------------------------------------------
// Scan phase B: one wave scans <=64 block partials (exclusive), total at part[NB].
// ---------------------------------------------------------------------------
__global__ void scanB_kernel(int* __restrict__ part, int NB) {
    const int t = threadIdx.x;  // 64 threads
    int orig = (t < NB) ? part[t] : 0;
    int v = orig;
    for (int o = 1; o < 64; o <<= 1) {
        int u = __shfl_up(v, o);
        if (t >= o) v += u;
    }
    if (t < NB) part[t] = v - orig;
    if (t == 63) part[NB] = v;
}

// ---------------------------------------------------------------------------
// Scan phase C: off[i] += part[i / SCAN_CHUNK]; off[N] = total;
// also emit bucket write-cursors bcur[b] = off[b*256].
// ---------------------------------------------------------------------------
__global__ void scanC_kernel(int* __restrict__ off, const int* __restrict__ part,
                             int* __restrict__ bcur, int N, int NB) {
    const int i = blockIdx.x * blockDim.x + threadIdx.x;  // over N/4 int4s
    const int n4 = N >> 2;
    if (i >= n4) return;
    const int p = part[i >> 8];
    int4 v = *(const int4*)(off + i * 4);
    v.x += p; v.y += p; v.z += p; v.w += p;
    *(int4*)(off + i * 4) = v;
    if ((i & 63) == 0) bcur[i >> 6] = v.x;   // node i*4 is multiple of 256
    if (i == 0) off[N] = part[NB];
}

// ---------------------------------------------------------------------------
// Kernel 3a: bucket fill. Entry = src | et<<16 | (dst&255)<<19.
// ---------------------------------------------------------------------------
__global__ void bfill_kernel(const int* __restrict__ dst, const int* __restrict__ srcv,
                             const int* __restrict__ et, int* __restrict__ bcur,
                             int* __restrict__ tmp, int E) {
    __shared__ int hist[256];
    __shared__ int base[256];
    __shared__ int lcur[256];
    const int t = threadIdx.x;
    hist[t] = 0; lcur[t] = 0;
    __syncthreads();
    const int e0 = blockIdx.x * EPB;
    int bk[8], pk[8];
#pragma unroll
    for (int k = 0; k < 8; k++) {
        int e = e0 + t + k * 256;
        if (e < E) {
            int dd = dst[e];
            bk[k] = dd >> 8;
            pk[k] = (srcv[e] & 0xFFFF) | (et[e] << 16) | ((dd & 255) << 19);
            atomicAdd(&hist[bk[k]], 1);
        } else bk[k] = -1;
    }
    __syncthreads();
    if (t < NBUCK && hist[t] > 0) base[t] = atomicAdd(&bcur[t], hist[t]);
    __syncthreads();
#pragma unroll
    for (int k = 0; k < 8; k++) {
        if (bk[k] >= 0) {
            int r = atomicAdd(&lcur[bk[k]], 1);
            tmp[base[bk[k]] + r] = pk[k];
        }
    }
}

// ---------------------------------------------------------------------------
// Kernel 3b: exact sort within bucket (one block per bucket).
// ---------------------------------------------------------------------------
__global__ void sort2_kernel(const int* __restrict__ off, const int* __restrict__ tmp,
                             int* __restrict__ spk, int N) {
    __shared__ int gcur[256];
    const int b = blockIdx.x;
    const int t = threadIdx.x;
    const int n0 = b * 256;
    const int nn = min(256, N - n0);
    if (t < nn) gcur[t] = off[n0 + t];
    __syncthreads();
    const int s0 = off[n0];
    const int s1 = off[(n0 + 256 < N) ? (n0 + 256) : N];
    for (int i = s0 + t; i < s1; i += 256) {
        int e = tmp[i];
        int dlo = (e >> 19) & 255;
        int pos = atomicAdd(&gcur[dlo], 1);
        spk[pos] = e;
    }
}

// ---------------------------------------------------------------------------
// Kernel 4: prep. Blocks [0,WTB): WtT[f][r*64+d] = bf16(W[r][d][f]) (64 KB).
// Blocks [WTB,...): featb = bf16(feat) (6.4 MB, L2-resident gather target).
// ---------------------------------------------------------------------------
__global__ void prep_kernel(const float* __restrict__ feat, const float* __restrict__ W,
                            unsigned short* __restrict__ featb,
                            unsigned short* __restrict__ WtT, int N) {
    const int bid = blockIdx.x;
    if (bid < WTB) {
        int i4 = bid * 256 + threadIdx.x;          // [0, 8192) float4s of W
        float4 v = ((const float4*)W)[i4];
        int base = i4 * 4;                         // element index
        int f0 = base & 63;
        int d  = (base >> 6) & 63;
        int r  = base >> 12;
        int k  = r * 64 + d;
        WtT[(f0 + 0) * 512 + k] = f2b(v.x);
        WtT[(f0 + 1) * 512 + k] = f2b(v.y);
        WtT[(f0 + 2) * 512 + k] = f2b(v.z);
        WtT[(f0 + 3) * 512 + k] = f2b(v.w);
    } else {
        int i = (bid - WTB) * 256 + threadIdx.x;   // float4 index over feat
        if (i < N * 16) {
            float4 v = ((const float4*)feat)[i];
            ushort4 b;
            b.x = f2b(v.x); b.y = f2b(v.y); b.z = f2b(v.z); b.w = f2b(v.w);
            ((ushort4*)featb)[i] = b;
        }
    }
}

// ---------------------------------------------------------------------------
// Kernel 5: FUSED aggregate + transform + epilogue. Block = 1024 thr (16 waves),
// 64 dst nodes per block.
// Phase 1: wave w aggregates nodes w*4..w*4+3 (lane = dim, coalesced 128 B
//   gathers from bf16 featb; per-relation fp32 accum; rel is wave-uniform).
//   Result -> LDS agg[64][520] bf16 (row stride 520 = 1040 B, 2-way banks).
// Phase 2: waves 0..3: [16 x 512] @ [512 x 64] via 64 MFMAs (B-frags streamed
//   from global WtT, L2-broadcast), fused relu(0.2 f + 0.8 sum/deg) epilogue.
// ---------------------------------------------------------------------------
#define ACCADD(pk, v) { int rr = ((pk) >> 16) & 7;                      \
    switch (rr) {                                                       \
        case 0: a0 += (v); break; case 1: a1 += (v); break;             \
        case 2: a2 += (v); break; case 3: a3 += (v); break;             \
        case 4: a4 += (v); break; case 5: a5 += (v); break;             \
        case 6: a6 += (v); break; default: a7 += (v); break; } }

__global__ void __launch_bounds__(1024)
fused_kernel(const int* __restrict__ off, const int* __restrict__ spk,
             const unsigned short* __restrict__ featb,
             const unsigned short* __restrict__ WtT,
             const float* __restrict__ feat, float* __restrict__ out, int N) {
    __shared__ unsigned short agg[64 * 520];
    __shared__ int degs[64];
    const int n0   = blockIdx.x * 64;
    const int w    = threadIdx.x >> 6;     // wave 0..15
    const int lane = threadIdx.x & 63;

    // ---------------- Phase 1: aggregation ----------------
#pragma unroll
    for (int k = 0; k < 4; k++) {
        const int nl = w * 4 + k;
        const int node = n0 + nl;
        float a0 = 0.f, a1 = 0.f, a2 = 0.f, a3 = 0.f;
        float a4 = 0.f, a5 = 0.f, a6 = 0.f, a7 = 0.f;
        int deg = 0;
        if (node < N) {
            const int b = off[node], e = off[node + 1];
            deg = e - b;
            int i = b;
            while (i + 4 <= e) {
                int p0 = spk[i], p1 = spk[i + 1], p2 = spk[i + 2], p3 = spk[i + 3];
                float v0 = b2f(featb[((p0 & 0xFFFF) << 6) + lane]);
                float v1 = b2f(featb[((p1 & 0xFFFF) << 6) + lane]);
                float v2 = b2f(featb[((p2 & 0xFFFF) << 6) + lane]);
                float v3 = b2f(featb[((p3 & 0xFFFF) << 6) + lane]);
                ACCADD(p0, v0); ACCADD(p1, v1); ACCADD(p2, v2); ACCADD(p3, v3);
                i += 4;
            }
            while (i < e) {
                int p0 = spk[i];
                float v0 = b2f(featb[((p0 & 0xFFFF) << 6) + lane]);
                ACCADD(p0, v0);
                i++;
            }
        }
        unsigned short* row = &agg[nl * 520];
        row[0 * 64 + lane] = f2b(a0);
        row[1 * 64 + lane] = f2b(a1);
        row[2 * 64 + lane] = f2b(a2);
        row[3 * 64 + lane] = f2b(a3);
        row[4 * 64 + lane] = f2b(a4);
        row[5 * 64 + lane] = f2b(a5);
        row[6 * 64 + lane] = f2b(a6);
        row[7 * 64 + lane] = f2b(a7);
        if (lane == 0) degs[nl] = deg;
    }
    __syncthreads();
    if (w >= 4) return;

    // ---------------- Phase 2: MFMA transform ----------------
    const int col = lane & 15, quad = lane >> 4;
    f32x4 c0 = {0.f, 0.f, 0.f, 0.f}, c1 = c0, c2 = c0, c3 = c0;
    const unsigned short* arow = &agg[(w * 16 + col) * 520];   // A row m=col
#pragma unroll
    for (int kk = 0; kk < 16; kk++) {
        const int k0 = kk * 32 + quad * 8;
        bf16x8 av = *(const bf16x8*)&arow[k0];
        bf16x8 b0 = *(const bf16x8*)&WtT[(0 * 16 + col) * 512 + k0];
        bf16x8 b1 = *(const bf16x8*)&WtT[(1 * 16 + col) * 512 + k0];
        bf16x8 b2 = *(const bf16x8*)&WtT[(2 * 16 + col) * 512 + k0];
        bf16x8 b3 = *(const bf16x8*)&WtT[(3 * 16 + col) * 512 + k0];
        c0 = __builtin_amdgcn_mfma_f32_16x16x32_bf16(av, b0, c0, 0, 0, 0);
        c1 = __builtin_amdgcn_mfma_f32_16x16x32_bf16(av, b1, c1, 0, 0, 0);
        c2 = __builtin_amdgcn_mfma_f32_16x16x32_bf16(av, b2, c2, 0, 0, 0);
        c3 = __builtin_amdgcn_mfma_f32_16x16x32_bf16(av, b3, c3, 0, 0, 0);
    }

    // ---------------- Epilogue ----------------
#pragma unroll
    for (int i = 0; i < 4; i++) {
        const int nl = w * 16 + quad * 4 + i;
        const int node = n0 + nl;
        if (node >= N) continue;
        const int dg = degs[nl];
        const float inv = (dg > 0) ? (0.8f / (float)dg) : 0.f;
        const float sums[4] = {c0[i], c1[i], c2[i], c3[i]};
#pragma unroll
        for (int ft = 0; ft < 4; ft++) {
            const int f = ft * 16 + col;
            float fv = feat[(size_t)node * 64 + f];
            float res = (dg > 0) ? fmaxf(0.2f * fv + sums[ft] * inv, 0.f) : fv;
            out[(size_t)node * 64 + f] = res;
        }
    }
}

// ---------------------------------------------------------------------------
// Fallback kernels (small workspace): on-the-fly transform + atomics (fp32).
// ---------------------------------------------------------------------------
__global__ void degf_kernel(const int* __restrict__ dst, float* __restrict__ deg, int E) {
    int e = blockIdx.x * blockDim.x + threadIdx.x;
    if (e < E) atomicAdd(deg + dst[e], 1.0f);
}

__global__ void otf_kernel(const int* __restrict__ src, const int* __restrict__ dst,
                           const int* __restrict__ et, const float* __restrict__ feat,
                           const float* __restrict__ W, float* __restrict__ out, int E) {
    int wid = (blockIdx.x * blockDim.x + threadIdx.x) >> 6;
    int l = threadIdx.x & 63;
    if (wid >= E) return;
    int s = src[wid], dd = dst[wid], r = et[wid];
    float fv = feat[(size_t)s * 64 + l];
    const float* Wr = W + (size_t)r * 4096;
    float acc = 0.f;
#pragma unroll
    for (int d = 0; d < 64; d++) {
        float a = __shfl(fv, d);
        acc += a * Wr[d * 64 + l];
    }
    atomicAdd(out + (size_t)dd * 64 + l, acc);
}

__global__ void final_kernel(const float* __restrict__ feat, const float* __restrict__ deg,
                             float* __restrict__ out, int N) {
    int i = blockIdx.x * blockDim.x + threadIdx.x;
    if (i >= N * 16) return;
    int n = i >> 4;
    float d = deg[n];
    float4 f = ((const float4*)feat)[i];
    float4 m = ((float4*)out)[i];
    float4 res;
    if (d > 0.f) {
        float inv = 0.8f / d;
        res.x = fmaxf(0.2f * f.x + m.x * inv, 0.f);
        res.y = fmaxf(0.2f * f.y + m.y * inv, 0.f);
        res.z = fmaxf(0.2f * f.z + m.z * inv, 0.f);
        res.w = fmaxf(0.2f * f.w + m.w * inv, 0.f);
    } else {
        res = f;
    }
    ((float4*)out)[i] = res;
}

extern "C" void kernel_launch(void* const* d_in, const int* in_sizes, int n_in,
                              void* d_out, int out_size, void* d_ws, size_t ws_size,
                              hipStream_t stream) {
    const float* feat = (const float*)d_in[0];   // [N, 64]
    const float* W    = (const float*)d_in[1];   // [8, 64, 64]
    const int*   src  = (const int*)d_in[2];     // [E]
    const int*   dst  = (const int*)d_in[3];     // [E]
    const int*   et   = (const int*)d_in[4];     // [E]
    float* out = (float*)d_out;                  // [N, 64]

    const int N = N_NODES, E = N_EDGES;
    const int NB = (N + SCAN_CHUNK - 1) / SCAN_CHUNK;   // 49

    // Workspace layout:
    char* p = (char*)d_ws;
    int* cnt  = (int*)p;  p += align256((size_t)N * 4);
    int* off  = (int*)p;  p += align256((size_t)(N + 1) * 4);
    int* part = (int*)p;  p += align256((size_t)(NB + 1) * 4);
    int* bcur = (int*)p;  p += align256((size_t)256 * 4);
    int* tmp  = (int*)p;  p += align256((size_t)E * 4);
    int* spk  = (int*)p;  p += align256((size_t)E * 4);
    unsigned short* featb = (unsigned short*)p;  p += align256((size_t)N * FEAT * 2);
    unsigned short* WtT   = (unsigned short*)p;  p += align256((size_t)NRELS * FEAT * FEAT * 2);
    size_t need_full = (size_t)(p - (char*)d_ws);

    if (ws_size >= need_full) {
        hipMemsetAsync(cnt, 0, (size_t)N * 4, stream);
        hist_kernel<<<(E + 255) / 256, 256, 0, stream>>>(dst, cnt, E);
        scanA_kernel<<<NB, 256, 0, stream>>>(cnt, off, part, N);
        scanB_kernel<<<1, 64, 0, stream>>>(part, NB);
        scanC_kernel<<<((N >> 2) + 255) / 256, 256, 0, stream>>>(off, part, bcur, N, NB);
        bfill_kernel<<<(E + EPB - 1) / EPB, 256, 0, stream>>>(dst, src, et, bcur, tmp, E);
        sort2_kernel<<<NBUCK, 256, 0, stream>>>(off, tmp, spk, N);
        prep_kernel<<<WTB + (N * 16 + 255) / 256, 256, 0, stream>>>(feat, W, featb, WtT, N);
        fused_kernel<<<(N + 63) / 64, 1024, 0, stream>>>(off, spk, featb, WtT, feat, out, N);
    } else {
        // Minimal-workspace fallback.
        float* deg = (float*)d_ws;
        hipMemsetAsync(out, 0, (size_t)N * FEAT * 4, stream);
        hipMemsetAsync(deg, 0, (size_t)N * 4, stream);
        degf_kernel<<<(E + 255) / 256, 256, 0, stream>>>(dst, deg, E);
        otf_kernel<<<(E + 3) / 4, 256, 0, stream>>>(src, dst, et, feat, W, out, E);
        final_kernel<<<(N * 16 + 255) / 256, 256, 0, stream>>>(feat, deg, out, N);
    }
}